// Round 1
// 923.354 us; speedup vs baseline: 1.0012x; 1.0012x over previous
//
#include <hip/hip_runtime.h>

// UniformShardedEmbeddingBags: per-table embedding bag, sum pooling.
// weights: [E=200000, T=16, D=64] fp32  (row (e,t) is 256 B contiguous, 256 B aligned)
// indices: [B=4096, T=16, L=20] int32
// out:     [B, T, D] fp32
//
// Layout: block = 256 threads = one batch row b = 16 bags (all T tables).
//   - The block's indices are one contiguous [T][L] = 320-int slab -> staged
//     coalesced through LDS once (kills the 20 redundant 16-way-broadcast
//     vmem loads per bag and the idx->gather vmcnt dependency chain).
//   - 16 lanes per bag, each lane owns a float4 (4 of D=64 floats); one wave
//     gathers 4 rows x 256 B = 1 KiB per instruction.
//   - 32-bit addressing: byte offset = (e << 12) | (t*256 + sub*16).
//     e < 200000 -> e*4096 < 2^30, low 12 bits of e<<12 are zero, so OR is
//     exact; compiler emits SGPR-base + 32-bit VGPR-offset global_load_dwordx4.

constexpr int E = 200000;
constexpr int T = 16;
constexpr int D = 64;
constexpr int B = 4096;
constexpr int L = 20;

__global__ __launch_bounds__(256) void embed_bag_kernel(
    const float* __restrict__ w,      // [E, T, D]
    const int* __restrict__ idx,      // [B, T, L]
    float* __restrict__ out)          // [B, T, D]
{
    __shared__ int s_idx[T * L];      // 320 ints = 1.25 KiB

    const int b   = blockIdx.x;       // batch row
    const int tid = threadIdx.x;

    // Stage this b's whole index slab, fully coalesced (320 contiguous ints).
    const int* __restrict__ slab = idx + (size_t)b * (T * L);
    if (tid < T * L) s_idx[tid] = slab[tid];
    {
        const int k = tid + 256;
        if (k < T * L) s_idx[k] = slab[k];
    }
    __syncthreads();

    const int t   = tid >> 4;         // table id = local bag id
    const int sub = tid & 15;         // which float4 of the D=64 row

    // Per-lane constant byte offset within a 4 KiB weights super-row.
    const unsigned lane_off = (unsigned)(t * 256 + sub * 16);
    const char* __restrict__ wb = (const char*)w;

    // Pull the bag's 20 indices into registers (LDS broadcast reads,
    // bank-conflict-free: per wave the 4 groups hit distinct banks).
    int e[L];
#pragma unroll
    for (int l = 0; l < L; ++l) e[l] = s_idx[t * L + l];

    // 20 independent 1 KiB/wave gathers, no intervening vmem dependencies.
    float4 acc = make_float4(0.f, 0.f, 0.f, 0.f);
#pragma unroll
    for (int l = 0; l < L; ++l) {
        const unsigned off = ((unsigned)e[l] << 12) | lane_off;
        const float4 v = *(const float4*)(wb + off);
        acc.x += v.x; acc.y += v.y; acc.z += v.z; acc.w += v.w;
    }

    // Coalesced float4 store: out[b][t][sub*4 .. sub*4+3]
    *(float4*)(out + ((size_t)(b * T + t) * D) + sub * 4) = acc;
}

extern "C" void kernel_launch(void* const* d_in, const int* in_sizes, int n_in,
                              void* d_out, int out_size, void* d_ws, size_t ws_size,
                              hipStream_t stream) {
    const float* w  = (const float*)d_in[0];
    const int* idx  = (const int*)d_in[1];
    float* out      = (float*)d_out;

    // One block per batch row: grid = B = 4096 blocks of 256 threads.
    embed_bag_kernel<<<B, 256, 0, stream>>>(w, idx, out);
}